// Round 7
// baseline (348.090 us; speedup 1.0000x reference)
//
#include <hip/hip_runtime.h>
#include <hip/hip_bf16.h>
#include <math.h>

#define Hdim 128
#define Kn 48
#define NN 4096
#define FFH 512
#define LN_EPS 1e-5f

typedef __attribute__((ext_vector_type(8))) short bf16x8;
typedef __attribute__((ext_vector_type(4))) float floatx4;
typedef unsigned short ushort_t;

// chunk-major LDS tile: element (row,col) -> (col/8)*784 + row*16 + (col%8)*2
#define CMA(row, col) ((((col) >> 3) * 784) + ((row) << 4) + (((col)&7) << 1))

// tanh-approx GELU (|err vs erf-gelu| < ~3e-3)
__device__ __forceinline__ float gelu_f(float x) {
    float x2 = x * x;
    float u = x * fmaf(x2, -0.1029454f, -2.3022081f);
    return x * __builtin_amdgcn_rcpf(1.0f + exp2f(u));
}

__device__ __forceinline__ ushort_t f2bf(float f) {
    __hip_bfloat16 h = __float2bfloat16(f);
    return *reinterpret_cast<ushort_t*>(&h);
}
__device__ __forceinline__ float bf2f(ushort_t h) {
    union { unsigned u; float f; } v;
    v.u = ((unsigned)h) << 16;
    return v.f;
}

// ---------------------------------------------------------------------------
// convert_all: blocks 0..271   : weight transposes -> fragment-linear bf16
//              blocks 272..527 : hV fp32 -> bf16 (coalesced)
//              blocks 528..783 : pre_self GEMV (selfA = b1 + hV @ W1[0:128])
// fragment-linear: W'(n,k) at ((n>>4)*KD32 + (k>>5))*512 + ((k>>3)&3)*128
//                  + (n&15)*8 + (k&7)    (ushort units; KD32 = K/32)
// ---------------------------------------------------------------------------
__global__ __launch_bounds__(256) void convert_all(
    const float* __restrict__ W1, const float* __restrict__ W11,
    const float* __restrict__ W2, const float* __restrict__ W3,
    const float* __restrict__ W12, const float* __restrict__ W13,
    const float* __restrict__ W_in, const float* __restrict__ W_out,
    const float* __restrict__ hV, const float* __restrict__ b1,
    ushort_t* __restrict__ Wt1m, ushort_t* __restrict__ Wt11m,
    ushort_t* __restrict__ Wt11a, ushort_t* __restrict__ Wt2,
    ushort_t* __restrict__ Wt3, ushort_t* __restrict__ Wt12,
    ushort_t* __restrict__ Wt13, ushort_t* __restrict__ WtIn,
    ushort_t* __restrict__ WtOut, ushort_t* __restrict__ hVbf,
    float* __restrict__ selfA) {
    __shared__ __align__(16) char cmem[8448];
    const int b = blockIdx.x, t = threadIdx.x;

    if (b < 272) {
        const float* src;
        ushort_t* dst;
        int K, C, rowOff, tile;
        if (b < 32)       { src = W1;   dst = Wt1m;  K = 256; C = 128; rowOff = 128; tile = b; }
        else if (b < 64)  { src = W11;  dst = Wt11m; K = 256; C = 128; rowOff = 128; tile = b - 32; }
        else if (b < 80)  { src = W11;  dst = Wt11a; K = 128; C = 128; rowOff = 0;   tile = b - 64; }
        else if (b < 96)  { src = W2;   dst = Wt2;   K = 128; C = 128; rowOff = 0;   tile = b - 80; }
        else if (b < 112) { src = W3;   dst = Wt3;   K = 128; C = 128; rowOff = 0;   tile = b - 96; }
        else if (b < 128) { src = W12;  dst = Wt12;  K = 128; C = 128; rowOff = 0;   tile = b - 112; }
        else if (b < 144) { src = W13;  dst = Wt13;  K = 128; C = 128; rowOff = 0;   tile = b - 128; }
        else if (b < 208) { src = W_in; dst = WtIn;  K = 128; C = 512; rowOff = 0;   tile = b - 144; }
        else              { src = W_out;dst = WtOut; K = 512; C = 128; rowOff = 0;   tile = b - 208; }
        const int tpr = C >> 5;
        const int tk = tile / tpr, tn = tile % tpr;
        const int tr0 = tk * 32, tc0 = tn * 32;
        const int KD32 = K >> 5;
        float (*s)[33] = (float(*)[33])cmem;
#pragma unroll
        for (int i = 0; i < 4; ++i) {
            int r = (t >> 5) + i * 8, c = t & 31;
            s[r][c] = src[(size_t)(rowOff + tr0 + r) * C + tc0 + c];
        }
        __syncthreads();
        if (t < 128) {
            int n_loc = t >> 2, kc0 = (t & 3) * 8;
            int n = tc0 + n_loc, k = tr0 + kc0;
            ushort_t o[8];
#pragma unroll
            for (int e = 0; e < 8; ++e) o[e] = f2bf(s[kc0 + e][n_loc]);
            size_t idx = (size_t)((n >> 4) * KD32 + (k >> 5)) * 512 +
                         ((k >> 3) & 3) * 128 + (n & 15) * 8;
            *(uint4*)(dst + idx) = *(const uint4*)o;
        }
    } else if (b < 528) {
        int i = (b - 272) * 2048 + t * 8;
        float4 a = *(const float4*)(hV + (size_t)i);
        float4 c = *(const float4*)(hV + (size_t)i + 4);
        ushort_t o[8] = {f2bf(a.x), f2bf(a.y), f2bf(a.z), f2bf(a.w),
                         f2bf(c.x), f2bf(c.y), f2bf(c.z), f2bf(c.w)};
        *(uint4*)(hVbf + (size_t)i) = *(const uint4*)o;
    } else {
        float (*xs)[Hdim] = (float(*)[Hdim])cmem;
        const int grp = t >> 7, o = t & 127;
        const int nb0 = (b - 528) * 16;
#pragma unroll
        for (int n = 0; n < 8; ++n)
            xs[grp * 8 + n][o] = hV[(size_t)(nb0 + grp * 8 + n) * Hdim + o];
        __syncthreads();
        float acc[8];
        const float bo = b1[o];
#pragma unroll
        for (int n = 0; n < 8; ++n) acc[n] = bo;
        for (int i = 0; i < Hdim; i += 4) {
            const float w0 = W1[(i + 0) * Hdim + o];
            const float w1 = W1[(i + 1) * Hdim + o];
            const float w2 = W1[(i + 2) * Hdim + o];
            const float w3 = W1[(i + 3) * Hdim + o];
#pragma unroll
            for (int n = 0; n < 8; ++n) {
                const float4 v = *(const float4*)&xs[grp * 8 + n][i];
                acc[n] = fmaf(v.x, w0, acc[n]);
                acc[n] = fmaf(v.y, w1, acc[n]);
                acc[n] = fmaf(v.z, w2, acc[n]);
                acc[n] = fmaf(v.w, w3, acc[n]);
            }
        }
#pragma unroll
        for (int n = 0; n < 8; ++n)
            selfA[(size_t)(nb0 + grp * 8 + n) * Hdim + o] = acc[n];
    }
}

// ---------------------------------------------------------------------------
// edge_mlp<MODE>: 1 node/block, 256 threads (4 waves; wave w owns cols w*32..)
// T0 (25088B): chunks 0..15 = hE bf16 (kept for MODE1 residual);
//              chunks 16..31 = nbr gather -> L1out (overwrite) -> L2out
//              (in-place overwrite, barrier-separated). 6 blocks/CU.
// Weights fragment-linear in ws (L2-hot 16B/lane loads).
// MODE 0: masked col-sum /30, +hV, LN1 -> hV2.  MODE 1: +hE, row-LN3 -> out_hE
// ---------------------------------------------------------------------------
template <int MODE>
__global__ __launch_bounds__(256, 6) void edge_mlp(
    const float* __restrict__ hV, const float* __restrict__ hE,
    const int* __restrict__ Eidx, const float* __restrict__ maskAtt,
    const float* __restrict__ selfA, const ushort_t* __restrict__ hVbf,
    const ushort_t* __restrict__ WtA, const ushort_t* __restrict__ WtB,
    const ushort_t* __restrict__ WtC, const float* __restrict__ bias2,
    const float* __restrict__ bias3, const float* __restrict__ gamma,
    const float* __restrict__ beta, float* __restrict__ outp) {
    __shared__ __align__(16) char T0[32 * 784];   // 25088
    __shared__ __align__(16) char aux[1728];
    int* idx_s = (int*)aux;                 // [0,192)
    float* dh_s = (float*)(aux + 192);      // [192,704)   MODE0
    float* rw = (float*)(aux + 704);        // [704,736)   MODE0
    float2* rsums = (float2*)(aux + 192);   // [192,1728)  MODE1
    float* mu_s = (float*)(aux + 192);      // aliases rsums (wave-0 only)
    float* rs_s = (float*)(aux + 384);
    char* THI = T0 + 16 * 784;

    const int tid = threadIdx.x;
    const int lane = tid & 63;
    const int w = tid >> 6;
    const int l15 = lane & 15, l4 = lane >> 4;
    const int n = blockIdx.x;
    const int n0 = w * 32;
    const int bbase = (n >> 11) << 11;
    const int abase = l4 * 784 + l15 * 16;
    const int fbase = l4 * 128 + l15 * 8;

    if (tid < Kn) idx_s[tid] = Eidx[(size_t)n * Kn + tid];
    // stage hE (fp32 -> bf16, chunk-major, chunks 0..15)
    {
        const float4* src = (const float4*)(hE + (size_t)n * Kn * Hdim);
#pragma unroll
        for (int it = 0; it < 6; ++it) {
            int i = tid + it * 256;
            float4 v = src[i];
            int row = i >> 5, j = i & 31;
            unsigned lo = f2bf(v.x) | ((unsigned)f2bf(v.y) << 16);
            unsigned hi = f2bf(v.z) | ((unsigned)f2bf(v.w) << 16);
            *(uint2*)(T0 + (j >> 1) * 784 + row * 16 + (j & 1) * 8) =
                make_uint2(lo, hi);
        }
    }
    __syncthreads();
    // gather neighbor bf16 rows into chunks 16..31 (16B/lane)
#pragma unroll
    for (int it = 0; it < 3; ++it) {
        int i = tid + it * 256;
        int row = i >> 4, c = i & 15;
        uint4 v =
            *(const uint4*)(hVbf + (size_t)(bbase + idx_s[row]) * Hdim + c * 8);
        *(uint4*)(T0 + (16 + c) * 784 + row * 16) = v;
    }
    __syncthreads();

    floatx4 acc[3][2];
#pragma unroll
    for (int mt = 0; mt < 3; ++mt)
#pragma unroll
        for (int nt = 0; nt < 2; ++nt) acc[mt][nt] = (floatx4)0.0f;

    // ---- layer 1: K=256 (reads all of T0) ----
#pragma unroll
    for (int kk = 0; kk < 8; ++kk) {
        bf16x8 a[3], bb[2];
#pragma unroll
        for (int mt = 0; mt < 3; ++mt)
            a[mt] = *(const bf16x8*)(T0 + abase + mt * 256 + kk * 3136);
#pragma unroll
        for (int nt = 0; nt < 2; ++nt)
            bb[nt] = *(const bf16x8*)(WtA + ((w * 2 + nt) * 8 + kk) * 512 +
                                      fbase);
#pragma unroll
        for (int mt = 0; mt < 3; ++mt)
#pragma unroll
            for (int nt = 0; nt < 2; ++nt)
                acc[mt][nt] = __builtin_amdgcn_mfma_f32_16x16x32_bf16(
                    a[mt], bb[nt], acc[mt][nt], 0, 0, 0);
    }
    __syncthreads();  // all L1 reads done before overwriting THI
    // layer-1 epilogue: + selfA broadcast, GELU -> THI
    {
        float sA[2];
#pragma unroll
        for (int nt = 0; nt < 2; ++nt)
            sA[nt] = selfA[(size_t)n * Hdim + n0 + nt * 16 + l15];
#pragma unroll
        for (int mt = 0; mt < 3; ++mt)
#pragma unroll
            for (int nt = 0; nt < 2; ++nt) {
                const int col = n0 + nt * 16 + l15;
#pragma unroll
                for (int r = 0; r < 4; ++r) {
                    float v = gelu_f(acc[mt][nt][r] + sA[nt]);
                    int row = mt * 16 + l4 * 4 + r;
                    *(ushort_t*)(THI + CMA(row, col)) = f2bf(v);
                }
            }
    }
    __syncthreads();

    // ---- layer 2: K=128 (reads THI) ----
    {
        float bv[2];
#pragma unroll
        for (int nt = 0; nt < 2; ++nt) bv[nt] = bias2[n0 + nt * 16 + l15];
#pragma unroll
        for (int mt = 0; mt < 3; ++mt)
#pragma unroll
            for (int nt = 0; nt < 2; ++nt)
                acc[mt][nt] = (floatx4){bv[nt], bv[nt], bv[nt], bv[nt]};
    }
#pragma unroll
    for (int kk = 0; kk < 4; ++kk) {
        bf16x8 a[3], bb[2];
#pragma unroll
        for (int mt = 0; mt < 3; ++mt)
            a[mt] = *(const bf16x8*)(THI + abase + mt * 256 + kk * 3136);
#pragma unroll
        for (int nt = 0; nt < 2; ++nt)
            bb[nt] = *(const bf16x8*)(WtB + ((w * 2 + nt) * 4 + kk) * 512 +
                                      fbase);
#pragma unroll
        for (int mt = 0; mt < 3; ++mt)
#pragma unroll
            for (int nt = 0; nt < 2; ++nt)
                acc[mt][nt] = __builtin_amdgcn_mfma_f32_16x16x32_bf16(
                    a[mt], bb[nt], acc[mt][nt], 0, 0, 0);
    }
    __syncthreads();  // all L2 reads done before in-place overwrite
#pragma unroll
    for (int mt = 0; mt < 3; ++mt)
#pragma unroll
        for (int nt = 0; nt < 2; ++nt) {
            const int col = n0 + nt * 16 + l15;
#pragma unroll
            for (int r = 0; r < 4; ++r) {
                float v = gelu_f(acc[mt][nt][r]);
                int row = mt * 16 + l4 * 4 + r;
                *(ushort_t*)(THI + CMA(row, col)) = f2bf(v);
            }
        }
    __syncthreads();

    // ---- layer 3: K=128 (reads THI), no activation ----
    {
        float bv[2];
#pragma unroll
        for (int nt = 0; nt < 2; ++nt) bv[nt] = bias3[n0 + nt * 16 + l15];
#pragma unroll
        for (int mt = 0; mt < 3; ++mt)
#pragma unroll
            for (int nt = 0; nt < 2; ++nt)
                acc[mt][nt] = (floatx4){bv[nt], bv[nt], bv[nt], bv[nt]};
    }
#pragma unroll
    for (int kk = 0; kk < 4; ++kk) {
        bf16x8 a[3], bb[2];
#pragma unroll
        for (int mt = 0; mt < 3; ++mt)
            a[mt] = *(const bf16x8*)(THI + abase + mt * 256 + kk * 3136);
#pragma unroll
        for (int nt = 0; nt < 2; ++nt)
            bb[nt] = *(const bf16x8*)(WtC + ((w * 2 + nt) * 4 + kk) * 512 +
                                      fbase);
#pragma unroll
        for (int mt = 0; mt < 3; ++mt)
#pragma unroll
            for (int nt = 0; nt < 2; ++nt)
                acc[mt][nt] = __builtin_amdgcn_mfma_f32_16x16x32_bf16(
                    a[mt], bb[nt], acc[mt][nt], 0, 0, 0);
    }

    if (MODE == 0) {
        float mav[3][4];
#pragma unroll
        for (int mt = 0; mt < 3; ++mt)
#pragma unroll
            for (int r = 0; r < 4; ++r)
                mav[mt][r] = maskAtt[(size_t)n * Kn + mt * 16 + l4 * 4 + r];
#pragma unroll
        for (int nt = 0; nt < 2; ++nt) {
            float c = 0.0f;
#pragma unroll
            for (int mt = 0; mt < 3; ++mt)
#pragma unroll
                for (int r = 0; r < 4; ++r)
                    c = fmaf(mav[mt][r], acc[mt][nt][r], c);
            c += __shfl_xor(c, 16);
            c += __shfl_xor(c, 32);
            if (l4 == 0) dh_s[n0 + nt * 16 + l15] = c;
        }
        __syncthreads();
        float x = 0.0f;
        if (tid < 128) {
            x = hV[(size_t)n * Hdim + tid] + dh_s[tid] * (1.0f / 30.0f);
            float s = x, s2 = x * x;
#pragma unroll
            for (int off = 32; off > 0; off >>= 1) {
                s += __shfl_xor(s, off);
                s2 += __shfl_xor(s2, off);
            }
            if (lane == 0) {
                rw[w * 2] = s;
                rw[w * 2 + 1] = s2;
            }
        }
        __syncthreads();
        if (tid < 128) {
            const float ts = rw[0] + rw[2], ts2 = rw[1] + rw[3];
            const float mu = ts * (1.0f / Hdim);
            const float var = ts2 * (1.0f / Hdim) - mu * mu;
            const float rs = rsqrtf(var + LN_EPS);
            outp[(size_t)n * Hdim + tid] =
                gamma[tid] * (x - mu) * rs + beta[tid];
        }
    } else {
        // residual (bf16 hE from T0 chunks 0..15) + per-row LN3 -> out_hE
        float xv[3][2][4];
#pragma unroll
        for (int mt = 0; mt < 3; ++mt)
#pragma unroll
            for (int nt = 0; nt < 2; ++nt) {
                const int col = n0 + nt * 16 + l15;
#pragma unroll
                for (int r = 0; r < 4; ++r) {
                    int row = mt * 16 + l4 * 4 + r;
                    ushort_t hv = *(const ushort_t*)(T0 + CMA(row, col));
                    xv[mt][nt][r] = acc[mt][nt][r] + bf2f(hv);
                }
            }
#pragma unroll
        for (int mt = 0; mt < 3; ++mt)
#pragma unroll
            for (int r = 0; r < 4; ++r) {
                float s = xv[mt][0][r] + xv[mt][1][r];
                float s2 = xv[mt][0][r] * xv[mt][0][r] +
                           xv[mt][1][r] * xv[mt][1][r];
#pragma unroll
                for (int off = 1; off < 16; off <<= 1) {
                    s += __shfl_xor(s, off);
                    s2 += __shfl_xor(s2, off);
                }
                if (l15 == 0) {
                    int row = mt * 16 + l4 * 4 + r;
                    rsums[row * 4 + w] = make_float2(s, s2);
                }
            }
        __syncthreads();
        if (tid < Kn) {
            // wave 0 only: lockstep reads of rsums complete before the
            // aliased mu_s/rs_s writes below (same instruction stream)
            float2 p0 = rsums[tid * 4 + 0], p1 = rsums[tid * 4 + 1];
            float2 p2 = rsums[tid * 4 + 2], p3 = rsums[tid * 4 + 3];
            float s = p0.x + p1.x + p2.x + p3.x;
            float s2 = p0.y + p1.y + p2.y + p3.y;
            float mu = s * (1.0f / Hdim);
            float var = s2 * (1.0f / Hdim) - mu * mu;
            mu_s[tid] = mu;
            rs_s[tid] = rsqrtf(var + LN_EPS);
        }
        __syncthreads();
        float gv[2], bv[2];
#pragma unroll
        for (int nt = 0; nt < 2; ++nt) {
            gv[nt] = gamma[n0 + nt * 16 + l15];
            bv[nt] = beta[n0 + nt * 16 + l15];
        }
#pragma unroll
        for (int mt = 0; mt < 3; ++mt)
#pragma unroll
            for (int nt = 0; nt < 2; ++nt) {
                const int col = n0 + nt * 16 + l15;
#pragma unroll
                for (int r = 0; r < 4; ++r) {
                    int row = mt * 16 + l4 * 4 + r;
                    float y = gv[nt] * (xv[mt][nt][r] - mu_s[row]) *
                                  rs_s[row] + bv[nt];
                    outp[((size_t)n * Kn + row) * Hdim + col] = y;
                }
            }
    }
}

// ---------------------------------------------------------------------------
// ffn_mfma: 8 nodes/block (M padded to 16), 256 threads (4 waves), 512 blocks
// y = LN2(x + gelu(x@W_in+b_in)@W_out+b_out)*maskV -> out fp32 + bf16 copy
// fused: selfA2 = b11 + y_bf16 @ W11[0:128]
// ---------------------------------------------------------------------------
__global__ __launch_bounds__(256) void ffn_mfma(
    const float* __restrict__ hV2, const ushort_t* __restrict__ WtIn,
    const float* __restrict__ b_in, const ushort_t* __restrict__ WtOut,
    const float* __restrict__ b_out, const ushort_t* __restrict__ Wt11a,
    const float* __restrict__ b11, const float* __restrict__ g2,
    const float* __restrict__ be2, const float* __restrict__ maskV,
    float* __restrict__ outp, ushort_t* __restrict__ outb,
    float* __restrict__ selfA2) {
    __shared__ __align__(16) char XF[16 * 272];   // 16x128 bf16 chunk-major
    __shared__ __align__(16) char HF[64 * 272];   // 16x512 bf16 chunk-major
    __shared__ float rsF[8][4], rs2F[8][4], muF[8], rstdF[8];

    const int tid = threadIdx.x;
    const int lane = tid & 63;
    const int w = tid >> 6;
    const int l15 = lane & 15, l4 = lane >> 4;
    const int rg0 = blockIdx.x * 8;
    const int fbase = l4 * 128 + l15 * 8;

    {   // stage 8 rows of hV2 -> XF rows 0..7; zero rows 8..15
        const float4* src = (const float4*)(hV2 + (size_t)rg0 * Hdim);
        float4 v = src[tid];
        int row = tid >> 5, j = tid & 31;
        unsigned lo = f2bf(v.x) | ((unsigned)f2bf(v.y) << 16);
        unsigned hi = f2bf(v.z) | ((unsigned)f2bf(v.w) << 16);
        *(uint2*)(XF + (j >> 1) * 272 + row * 16 + (j & 1) * 8) =
            make_uint2(lo, hi);
        if (tid < 128) {
            int c = tid >> 3, rr = tid & 7;
            *(uint4*)(XF + c * 272 + (8 + rr) * 16) = make_uint4(0, 0, 0, 0);
        }
    }
    __syncthreads();
    // L1: wave w -> cols w*128..+127 (8 col-tiles), K=128
    {
        floatx4 a1[8];
#pragma unroll
        for (int j = 0; j < 8; ++j) {
            float bv = b_in[(w * 8 + j) * 16 + l15];
            a1[j] = (floatx4){bv, bv, bv, bv};
        }
#pragma unroll
        for (int kk = 0; kk < 4; ++kk) {
            bf16x8 af = *(const bf16x8*)(XF + (kk * 4 + l4) * 272 + l15 * 16);
#pragma unroll
            for (int j = 0; j < 8; ++j) {
                bf16x8 bf = *(const bf16x8*)(WtIn +
                             ((w * 8 + j) * 4 + kk) * 512 + fbase);
                a1[j] = __builtin_amdgcn_mfma_f32_16x16x32_bf16(af, bf, a1[j],
                                                                0, 0, 0);
            }
        }
#pragma unroll
        for (int j = 0; j < 8; ++j) {
            const int col = (w * 8 + j) * 16 + l15;
#pragma unroll
            for (int r = 0; r < 4; ++r) {
                int row = l4 * 4 + r;
                *(ushort_t*)(HF + (col >> 3) * 272 + row * 16 +
                             ((col & 7) << 1)) = f2bf(gelu_f(a1[j][r]));
            }
        }
    }
    __syncthreads();
    // L2: wave w -> cols w*32..+31 (2 N-tiles), K=512
    floatx4 o2[2];
#pragma unroll
    for (int nt = 0; nt < 2; ++nt) {
        float bv = b_out[(w * 2 + nt) * 16 + l15];
        o2[nt] = (floatx4){bv, bv, bv, bv};
    }
#pragma unroll
    for (int kk = 0; kk < 16; ++kk) {
        bf16x8 af = *(const bf16x8*)(HF + (kk * 4 + l4) * 272 + l15 * 16);
#pragma unroll
        for (int nt = 0; nt < 2; ++nt) {
            bf16x8 bf = *(const bf16x8*)(WtOut +
                         ((w * 2 + nt) * 16 + kk) * 512 + fbase);
            o2[nt] = __builtin_amdgcn_mfma_f32_16x16x32_bf16(af, bf, o2[nt],
                                                             0, 0, 0);
        }
    }
    // epilogue: residual + LN2 + mask (rows l4*4+r, valid if l4<2)
    float xv[2][4];
#pragma unroll
    for (int nt = 0; nt < 2; ++nt) {
        const int col = (w * 2 + nt) * 16 + l15;
#pragma unroll
        for (int r = 0; r < 4; ++r) {
            int row = l4 * 4 + r;
            xv[nt][r] = (l4 < 2)
                ? hV2[(size_t)(rg0 + row) * Hdim + col] + o2[nt][r] : 0.0f;
        }
    }
#pragma unroll
    for (int r = 0; r < 4; ++r) {
        float s = xv[0][r] + xv[1][r];
        float s2 = xv[0][r] * xv[0][r] + xv[1][r] * xv[1][r];
#pragma unroll
        for (int off = 1; off < 16; off <<= 1) {
            s += __shfl_xor(s, off);
            s2 += __shfl_xor(s2, off);
        }
        if (l15 == 0 && l4 < 2) {
            rsF[l4 * 4 + r][w] = s;
            rs2F[l4 * 4 + r][w] = s2;
        }
    }
    __syncthreads();
    if (tid < 8) {
        float s = rsF[tid][0] + rsF[tid][1] + rsF[tid][2] + rsF[tid][3];
        float s2 = rs2F[tid][0] + rs2F[tid][1] + rs2F[tid][2] + rs2F[tid][3];
        float mu = s * (1.0f / Hdim);
        float var = s2 * (1.0f / Hdim) - mu * mu;
        muF[tid] = mu;
        rstdF[tid] = rsqrtf(var + LN_EPS);
    }
    __syncthreads();
    if (l4 < 2) {
#pragma unroll
        for (int nt = 0; nt < 2; ++nt) {
            const int col = (w * 2 + nt) * 16 + l15;
            float gvv = g2[col], bvv = be2[col];
#pragma unroll
            for (int r = 0; r < 4; ++r) {
                int row = l4 * 4 + r;
                float y = (gvv * (xv[nt][r] - muF[row]) * rstdF[row] + bvv) *
                          maskV[rg0 + row];
                ushort_t yb = f2bf(y);
                outp[(size_t)(rg0 + row) * Hdim + col] = y;
                outb[(size_t)(rg0 + row) * Hdim + col] = yb;
                *(ushort_t*)(XF + (col >> 3) * 272 + row * 16 +
                             ((col & 7) << 1)) = yb;
            }
        }
    }
    __syncthreads();
    // fused selfA2 GEMM: wave w -> cols w*32..+31, K=128
    {
        floatx4 sa[2];
#pragma unroll
        for (int nt = 0; nt < 2; ++nt) {
            float bv = b11[(w * 2 + nt) * 16 + l15];
            sa[nt] = (floatx4){bv, bv, bv, bv};
        }
#pragma unroll
        for (int kk = 0; kk < 4; ++kk) {
            bf16x8 af = *(const bf16x8*)(XF + (kk * 4 + l4) * 272 + l15 * 16);
#pragma unroll
            for (int nt = 0; nt < 2; ++nt) {
                bf16x8 bf = *(const bf16x8*)(Wt11a +
                             ((w * 2 + nt) * 4 + kk) * 512 + fbase);
                sa[nt] = __builtin_amdgcn_mfma_f32_16x16x32_bf16(af, bf,
                                                                 sa[nt], 0, 0, 0);
            }
        }
        if (l4 < 2) {
#pragma unroll
            for (int nt = 0; nt < 2; ++nt) {
                const int col = (w * 2 + nt) * 16 + l15;
#pragma unroll
                for (int r = 0; r < 4; ++r)
                    selfA2[(size_t)(rg0 + l4 * 4 + r) * Hdim + col] =
                        sa[nt][r];
            }
        }
    }
}

// ---------------------------------------------------------------------------
extern "C" void kernel_launch(void* const* d_in, const int* in_sizes, int n_in,
                              void* d_out, int out_size, void* d_ws,
                              size_t ws_size, hipStream_t stream) {
    const float* hV = (const float*)d_in[0];
    const float* hE = (const float*)d_in[1];
    const int* Eidx = (const int*)d_in[2];
    const float* maskV = (const float*)d_in[3];
    const float* maskAtt = (const float*)d_in[4];
    const float* W1 = (const float*)d_in[5];
    const float* b1 = (const float*)d_in[6];
    const float* W2 = (const float*)d_in[7];
    const float* b2 = (const float*)d_in[8];
    const float* W3 = (const float*)d_in[9];
    const float* b3 = (const float*)d_in[10];
    const float* W11 = (const float*)d_in[11];
    const float* b11 = (const float*)d_in[12];
    const float* W12 = (const float*)d_in[13];
    const float* b12 = (const float*)d_in[14];
    const float* W13 = (const float*)d_in[15];
    const float* b13 = (const float*)d_in[16];
    const float* g1 = (const float*)d_in[17];
    const float* be1 = (const float*)d_in[18];
    const float* g2 = (const float*)d_in[19];
    const float* be2 = (const float*)d_in[20];
    const float* g3 = (const float*)d_in[21];
    const float* be3 = (const float*)d_in[22];
    const float* W_in = (const float*)d_in[23];
    const float* b_in = (const float*)d_in[24];
    const float* W_out = (const float*)d_in[25];
    const float* b_out = (const float*)d_in[26];

    float* out_hV = (float*)d_out;
    float* out_hE = out_hV + (size_t)NN * Hdim;
    float* ws = (float*)d_ws;
    float* hV2 = ws;                       // 524288 f32
    float* selfA = ws + 524288;            // 524288 f32
    ushort_t* u = (ushort_t*)(ws + 1048576);
    ushort_t* hVbf = u;                    // 524288
    ushort_t* outVbf = u + 524288;         // 524288
    ushort_t* Wt1m = u + 1048576;          // 32768
    ushort_t* Wt11m = u + 1081344;         // 32768
    ushort_t* Wt11a = u + 1114112;         // 16384
    ushort_t* Wt2 = u + 1130496;           // 16384
    ushort_t* Wt3 = u + 1146880;           // 16384
    ushort_t* Wt12 = u + 1163264;          // 16384
    ushort_t* Wt13 = u + 1179648;          // 16384
    ushort_t* WtIn = u + 1196032;          // 65536
    ushort_t* WtOut = u + 1261568;         // 65536

    convert_all<<<784, 256, 0, stream>>>(W1, W11, W2, W3, W12, W13, W_in,
                                         W_out, hV, b1, Wt1m, Wt11m, Wt11a,
                                         Wt2, Wt3, Wt12, Wt13, WtIn, WtOut,
                                         hVbf, selfA);
    // phase 1: node message + LN1 -> hV2
    edge_mlp<0><<<NN, 256, 0, stream>>>(hV, hE, Eidx, maskAtt, selfA, hVbf,
                                        Wt1m, Wt2, Wt3, b2, b3, g1, be1, hV2);
    // phase 2: FFN + LN2 + mask -> out_hV (+ bf16 copy) + fused selfA2
    ffn_mfma<<<NN / 8, 256, 0, stream>>>(hV2, WtIn, b_in, WtOut, b_out,
                                         Wt11a, b11, g2, be2, maskV, out_hV,
                                         outVbf, selfA);
    // phase 3: edge update + LN3 -> out_hE
    edge_mlp<1><<<NN, 256, 0, stream>>>(nullptr, hE, Eidx, nullptr, selfA,
                                        outVbf, Wt11m, Wt12, Wt13, b12, b13,
                                        g3, be3, out_hE);
}